// Round 2
// 1840.425 us; speedup vs baseline: 1.1198x; 1.1198x over previous
//
#include <hip/hip_runtime.h>

#define NN 100000
#define NE 500000

typedef short v8s __attribute__((ext_vector_type(8)));
typedef float v4f __attribute__((ext_vector_type(4)));

__device__ __forceinline__ unsigned short f2bf(float f) {
    unsigned u = __float_as_uint(f);
    u += 0x7fffu + ((u >> 16) & 1u);
    return (unsigned short)(u >> 16);
}
__device__ __forceinline__ float bf2f(unsigned short h) {
    return __uint_as_float(((unsigned)h) << 16);
}
__device__ __forceinline__ unsigned pk2(float a, float b) {
    return (unsigned)f2bf(a) | ((unsigned)f2bf(b) << 16);
}
__device__ __forceinline__ float lo16(unsigned v) { return bf2f((unsigned short)(v & 0xffffu)); }
__device__ __forceinline__ float hi16(unsigned v) { return bf2f((unsigned short)(v >> 16)); }

// load channels (2*lane, 2*lane+1) of row `row` of a [rows,128] tensor (bf16 or f32)
__device__ __forceinline__ unsigned load2(const void* base, long row, int lane, int f) {
    if (f) return ((const unsigned*)base)[row * 64 + lane];
    const float2 v = ((const float2*)base)[row * 64 + lane];
    return pk2(v.x, v.y);
}

// ---------------- dtype detector ----------------
__global__ void detect_k(const unsigned short* __restrict__ edgeR, int* __restrict__ flag) {
    __shared__ int cnt;
    const int tid = threadIdx.x;
    if (tid == 0) cnt = 0;
    __syncthreads();
    const float v = fabsf(bf2f(edgeR[2 * tid]));
    const int sane = (v > 1e-5f && v < 100.f) ? 1 : 0;
    atomicAdd(&cnt, sane);
    __syncthreads();
    if (tid == 0) *flag = (cnt >= 128) ? 1 : 0;
}

// ---------------- CSR build: histogram -> scan -> fill ----------------
__global__ __launch_bounds__(256) void hist_k(const int* __restrict__ ep, int* __restrict__ deg) {
    const int i = blockIdx.x * 256 + threadIdx.x;
    if (i < 2 * NE) atomicAdd(&deg[ep[i]], 1);
}

__global__ __launch_bounds__(1024) void scan_k(int* __restrict__ degcur, int* __restrict__ rowptr) {
    __shared__ int sd[1024];
    const int t = threadIdx.x;
    const int base = t * 98;
    int sum = 0;
    for (int i = 0; i < 98; ++i) {
        const int idx = base + i;
        if (idx < NN) sum += degcur[idx];
    }
    sd[t] = sum;
    __syncthreads();
    for (int off = 1; off < 1024; off <<= 1) {
        const int v = (t >= off) ? sd[t - off] : 0;
        __syncthreads();
        sd[t] += v;
        __syncthreads();
    }
    int run = sd[t] - sum;   // exclusive prefix of this chunk
    for (int i = 0; i < 98; ++i) {
        const int idx = base + i;
        if (idx < NN) {
            const int d = degcur[idx];   // read BEFORE overwrite
            rowptr[idx] = run;
            degcur[idx] = run;           // becomes the fill cursor
            run += d;
        }
    }
    if (t == 0) rowptr[NN] = 2 * NE;
}

__global__ __launch_bounds__(256) void fill_k(const int* __restrict__ ep,
                                              int* __restrict__ cursor, int* __restrict__ csr) {
    const int i = blockIdx.x * 256 + threadIdx.x;
    if (i >= 2 * NE) return;
    const int n = ep[i];
    const int pos = atomicAdd(&cursor[n], 1);
    csr[pos] = (i < NE) ? i : (i - NE);
}

// ---------------- pack weights into MFMA B-fragment order ----------------
__global__ __launch_bounds__(256) void pack_weights(
    const void* __restrict__ W1, const void* __restrict__ Wn1,
    const void* __restrict__ Wn2, const void* __restrict__ We1,
    const void* __restrict__ We2, unsigned short* __restrict__ wpk,
    const int* __restrict__ flag)
{
    const int i = blockIdx.x * 256 + threadIdx.x;
    if (i >= 163840) return;
    const void* W; int Nn; int li = i;
    if (i < 32768)       { W = W1;  Nn = 128; }
    else if (i < 65536)  { W = Wn1; Nn = 256; li -= 32768; }
    else if (i < 98304)  { W = Wn2; Nn = 128; li -= 65536; }
    else if (i < 131072) { W = We1; Nn = 256; li -= 98304; }
    else                 { W = We2; Nn = 128; li -= 131072; }
    const int ntn = Nn >> 4;
    const int j = li & 7, l = (li >> 3) & 63, tile = li >> 9;
    const int ct = tile % ntn, kt = tile / ntn;
    const int k = kt * 32 + (l >> 4) * 8 + j;
    const int n = ct * 16 + (l & 15);
    const int idx = k * Nn + n;
    wpk[i] = (*flag) ? ((const unsigned short*)W)[idx]
                     : f2bf(((const float*)W)[idx]);
}

// ---------------- kernel A: gather + concat GEMM (lvl_mlp_1) + edge GEMM_e1 (stats only) ----------
// LDS: [64][256] shorts, XOR-swizzled (c ^= (row&7)<<3) -> exactly 32 KiB -> 5 blocks/CU
__global__ __launch_bounds__(256, 5) void kernel_A(
    const void* __restrict__ node, const void* __restrict__ edge,
    const int* __restrict__ ep,
    const unsigned short* __restrict__ wpk1, const unsigned short* __restrict__ wpkE1,
    unsigned short* __restrict__ y1, unsigned short* __restrict__ edge_in,
    float* __restrict__ stats, const void* __restrict__ eps2p, const int* __restrict__ flag)
{
    __shared__ unsigned short X[64 * 256];
    const int tid = threadIdx.x, wid = tid >> 6, lane = tid & 63;
    const int mrow = lane & 15, quad = lane >> 4;
    const int li = lane & 31, hb = lane >> 5;
    const int e0 = blockIdx.x * 64;
    const int e0w = e0 + wid * 16;
    const int bin = blockIdx.x & 31;
    const int f = *flag;

    // one coalesced endpoint-index load per wave (lanes 0..15 carry the 16 edges)
    const int ei = e0w + mrow;
    int sv = 0, tv = 0;
    if (ei < NE) { sv = ep[ei]; tv = ep[NE + ei]; }

    // gather: 2 rows per instruction (half-wave per row), 16B loads
    #pragma unroll
    for (int j = 0; j < 8; ++j) {
        const int eA = e0w + 2 * j + hb;
        const int s = __shfl(sv, 2 * j + hb);
        const int t = __shfl(tv, 2 * j + hb);
        uint2 lp = {0u, 0u}, ee = {0u, 0u};
        if (eA < NE) {
            if (f) {
                const uint2 a = ((const uint2*)node)[s * 32 + li];
                const uint2 b = ((const uint2*)node)[t * 32 + li];
                ee = ((const uint2*)edge)[(size_t)eA * 32 + li];
                lp.x = pk2(lo16(a.x) + lo16(b.x), hi16(a.x) + hi16(b.x));
                lp.y = pk2(lo16(a.y) + lo16(b.y), hi16(a.y) + hi16(b.y));
            } else {
                const float4 a = ((const float4*)node)[s * 32 + li];
                const float4 b = ((const float4*)node)[t * 32 + li];
                const float4 ev = ((const float4*)edge)[(size_t)eA * 32 + li];
                lp.x = pk2(a.x + b.x, a.y + b.y);
                lp.y = pk2(a.z + b.z, a.w + b.w);
                ee.x = pk2(ev.x, ev.y);
                ee.y = pk2(ev.z, ev.w);
            }
        }
        const int r = wid * 16 + 2 * j + hb;
        const int swz = (r & 7) << 3;
        *(uint2*)&X[r * 256 + ((li * 4) ^ swz)] = lp;
        *(uint2*)&X[r * 256 + ((128 + li * 4) ^ swz)] = ee;
    }
    __syncthreads();

    // GEMM1: X[64x256] @ W_lvl1[256x128] -> y1 + stats
    {
        v4f acc[4][2];
        #pragma unroll
        for (int rb = 0; rb < 4; ++rb)
            #pragma unroll
            for (int c = 0; c < 2; ++c)
                acc[rb][c] = (v4f){0.f, 0.f, 0.f, 0.f};
        const int ct0 = wid * 2;
        #pragma unroll
        for (int kt = 0; kt < 8; ++kt) {
            v8s a[4];
            #pragma unroll
            for (int rb = 0; rb < 4; ++rb) {
                const int r = rb * 16 + mrow;
                a[rb] = *(const v8s*)&X[r * 256 + ((kt * 32 + quad * 8) ^ ((r & 7) << 3))];
            }
            #pragma unroll
            for (int c = 0; c < 2; ++c) {
                const v8s b = ((const v8s*)wpk1)[(kt * 8 + ct0 + c) * 64 + lane];
                #pragma unroll
                for (int rb = 0; rb < 4; ++rb)
                    acc[rb][c] = __builtin_amdgcn_mfma_f32_16x16x32_bf16(a[rb], b, acc[rb][c], 0, 0, 0);
            }
        }
        #pragma unroll
        for (int c = 0; c < 2; ++c) {
            const int col = (ct0 + c) * 16 + mrow;
            float sy = 0.f, sq = 0.f;
            #pragma unroll
            for (int rb = 0; rb < 4; ++rb) {
                #pragma unroll
                for (int r4 = 0; r4 < 4; ++r4) {
                    const float v = acc[rb][c][r4];
                    const int e = e0 + rb * 16 + quad * 4 + r4;
                    if (e < NE) y1[(size_t)e * 128 + col] = f2bf(v);
                    sy += v; sq += v * v;
                }
            }
            sy += __shfl_xor(sy, 16); sy += __shfl_xor(sy, 32);
            sq += __shfl_xor(sq, 16); sq += __shfl_xor(sq, 32);
            if (quad == 0) {
                atomicAdd(&stats[bin * 1792 + col], sy);
                atomicAdd(&stats[bin * 1792 + 128 + col], sq);
            }
        }
    }
    __syncthreads();

    // rebuild edge_in = (1+eps2)*edge + lift into cols [0,128) and store to global
    const float e2 = 1.f + (f ? bf2f(((const unsigned short*)eps2p)[0])
                              : ((const float*)eps2p)[0]);
    #pragma unroll
    for (int rr = 0; rr < 16; ++rr) {
        const int r = wid * 16 + rr;
        const int swz = (r & 7) << 3;
        const unsigned lp = *(const unsigned*)&X[r * 256 + ((2 * lane) ^ swz)];
        const unsigned ee = *(const unsigned*)&X[r * 256 + ((128 + 2 * lane) ^ swz)];
        const unsigned o = pk2(fmaf(e2, lo16(ee), lo16(lp)), fmaf(e2, hi16(ee), hi16(lp)));
        *(unsigned*)&X[r * 256 + ((2 * lane) ^ swz)] = o;
        const int e = e0 + r;
        if (e < NE) ((unsigned*)edge_in)[(size_t)e * 64 + lane] = o;
    }
    __syncthreads();

    // GEMM_e1: edge_in[64x128] @ W_e1[128x256] -> stats ONLY (output recomputed in fused pass 2)
    {
        v4f acc[4][4];
        #pragma unroll
        for (int rb = 0; rb < 4; ++rb)
            #pragma unroll
            for (int c = 0; c < 4; ++c)
                acc[rb][c] = (v4f){0.f, 0.f, 0.f, 0.f};
        const int ct0 = wid * 4;
        #pragma unroll
        for (int kt = 0; kt < 4; ++kt) {
            v8s a[4];
            #pragma unroll
            for (int rb = 0; rb < 4; ++rb) {
                const int r = rb * 16 + mrow;
                a[rb] = *(const v8s*)&X[r * 256 + ((kt * 32 + quad * 8) ^ ((r & 7) << 3))];
            }
            #pragma unroll
            for (int c = 0; c < 4; ++c) {
                const v8s b = ((const v8s*)wpkE1)[(kt * 16 + ct0 + c) * 64 + lane];
                #pragma unroll
                for (int rb = 0; rb < 4; ++rb)
                    acc[rb][c] = __builtin_amdgcn_mfma_f32_16x16x32_bf16(a[rb], b, acc[rb][c], 0, 0, 0);
            }
        }
        #pragma unroll
        for (int c = 0; c < 4; ++c) {
            const int col = (ct0 + c) * 16 + mrow;
            float sy = 0.f, sq = 0.f;
            #pragma unroll
            for (int rb = 0; rb < 4; ++rb) {
                #pragma unroll
                for (int r4 = 0; r4 < 4; ++r4) {
                    const float v = acc[rb][c][r4];   // OOB rows are zero in X -> contribute 0
                    sy += v; sq += v * v;
                }
            }
            sy += __shfl_xor(sy, 16); sy += __shfl_xor(sy, 32);
            sq += __shfl_xor(sq, 16); sq += __shfl_xor(sq, 32);
            if (quad == 0) {
                atomicAdd(&stats[bin * 1792 + 256 + col], sy);
                atomicAdd(&stats[bin * 1792 + 512 + col], sq);
            }
        }
    }
}

// ---------------- finalize BN ----------------
__global__ void finalize_k(const float* __restrict__ stats, float* __restrict__ ab,
                           const void* __restrict__ g, const void* __restrict__ bb,
                           const int sOff, const int qOff, const int aOff, const int bOff,
                           const int n, const float invc, const int* __restrict__ flag)
{
    const int c = threadIdx.x;
    if (c >= n) return;
    float S = 0.f, Q = 0.f;
    for (int b = 0; b < 32; ++b) { S += stats[b * 1792 + sOff + c]; Q += stats[b * 1792 + qOff + c]; }
    const float mu = S * invc;
    const float var = Q * invc - mu * mu;
    const float gv = (*flag) ? bf2f(((const unsigned short*)g)[c]) : ((const float*)g)[c];
    const float bv = (*flag) ? bf2f(((const unsigned short*)bb)[c]) : ((const float*)bb)[c];
    const float a = gv * rsqrtf(var + 1e-5f);
    ab[aOff + c] = a;
    ab[bOff + c] = bv - a * mu;
}

// ---------------- node MLP layer 1 with fused CSR gather (stats only + node_in store) ----------
__global__ __launch_bounds__(256, 5) void gemm_node1(
    const void* __restrict__ node, const unsigned short* __restrict__ y1,
    const int* __restrict__ rowptr, const int* __restrict__ csr,
    const unsigned short* __restrict__ wpk, unsigned short* __restrict__ node_in,
    float* __restrict__ sS, float* __restrict__ sQ,
    const void* __restrict__ eps1p, const float* __restrict__ ab,
    const int* __restrict__ flag)
{
    __shared__ unsigned short X[64 * 128];   // [64][128] swizzled, 16 KiB
    const int tid = threadIdx.x, wid = tid >> 6, lane = tid & 63;
    const int mrow = lane & 15, quad = lane >> 4;
    const long r0 = (long)blockIdx.x * 64;
    const int bin = blockIdx.x & 31;
    const int f = *flag;
    const float ea = 1.f + (f ? bf2f(((const unsigned short*)eps1p)[0])
                              : ((const float*)eps1p)[0]);
    const int c0 = 2 * lane;
    const float a0 = ab[c0], a1 = ab[c0 + 1];
    const float b0 = ab[128 + c0], b1 = ab[128 + c0 + 1];

    for (int rr = 0; rr < 16; ++rr) {
        const int r = wid * 16 + rr;
        const long gr = r0 + r;
        unsigned o = 0;
        if (gr < NN) {
            float s0 = 0.f, s1 = 0.f;
            const int beg = rowptr[gr], end = rowptr[gr + 1];
            for (int i = beg; i < end; ++i) {
                const int e = csr[i];
                const unsigned v = ((const unsigned*)y1)[(size_t)e * 64 + lane];
                s0 += fmaxf(fmaf(a0, lo16(v), b0), 0.f);
                s1 += fmaxf(fmaf(a1, hi16(v), b1), 0.f);
            }
            const unsigned nr = load2(node, gr, lane, f);
            o = pk2(fmaf(ea, lo16(nr), s0), fmaf(ea, hi16(nr), s1));
        }
        *(unsigned*)&X[r * 128 + ((2 * lane) ^ ((r & 7) << 3))] = o;
        if (gr < NN) ((unsigned*)node_in)[gr * 64 + lane] = o;
    }
    __syncthreads();

    v4f acc[4][4];
    #pragma unroll
    for (int rb = 0; rb < 4; ++rb)
        #pragma unroll
        for (int c = 0; c < 4; ++c)
            acc[rb][c] = (v4f){0.f, 0.f, 0.f, 0.f};
    const int ct0 = wid * 4;
    #pragma unroll
    for (int kt = 0; kt < 4; ++kt) {
        v8s a[4];
        #pragma unroll
        for (int rb = 0; rb < 4; ++rb) {
            const int r = rb * 16 + mrow;
            a[rb] = *(const v8s*)&X[r * 128 + ((kt * 32 + quad * 8) ^ ((r & 7) << 3))];
        }
        #pragma unroll
        for (int c = 0; c < 4; ++c) {
            const v8s b = ((const v8s*)wpk)[(kt * 16 + ct0 + c) * 64 + lane];
            #pragma unroll
            for (int rb = 0; rb < 4; ++rb)
                acc[rb][c] = __builtin_amdgcn_mfma_f32_16x16x32_bf16(a[rb], b, acc[rb][c], 0, 0, 0);
        }
    }
    #pragma unroll
    for (int c = 0; c < 4; ++c) {
        const int col = (ct0 + c) * 16 + mrow;
        float sy = 0.f, sq = 0.f;
        #pragma unroll
        for (int rb = 0; rb < 4; ++rb) {
            #pragma unroll
            for (int r4 = 0; r4 < 4; ++r4) {
                const float v = acc[rb][c][r4];
                sy += v; sq += v * v;
            }
        }
        sy += __shfl_xor(sy, 16); sy += __shfl_xor(sy, 32);
        sq += __shfl_xor(sq, 16); sq += __shfl_xor(sq, 32);
        if (quad == 0) {
            atomicAdd(&sS[bin * 1792 + col], sy);
            atomicAdd(&sQ[bin * 1792 + col], sq);
        }
    }
}

// ---------------- fused pass-2: in[rows,128] -> GEMM1(128->256) -> BN+ReLU -> GEMM2(256->128) ----
__global__ __launch_bounds__(256, 5) void fused2_k(
    const unsigned short* __restrict__ in, const float* __restrict__ aab,
    const float* __restrict__ bab, const unsigned short* __restrict__ wpkA,
    const unsigned short* __restrict__ wpkB, unsigned short* __restrict__ out,
    float* __restrict__ sS, float* __restrict__ sQ, const long rows)
{
    __shared__ unsigned short X[64 * 256];   // 32 KiB, swizzled; reused for in-tile then mid-tile
    const int tid = threadIdx.x, wid = tid >> 6, lane = tid & 63;
    const int mrow = lane & 15, quad = lane >> 4;
    const long r0 = (long)blockIdx.x * 64;
    const int bin = blockIdx.x & 31;

    // phase 1: load in-tile [64][128] into cols [0,128) (4 rows per 16B instruction)
    #pragma unroll
    for (int i = 0; i < 4; ++i) {
        const int r = wid * 16 + i * 4 + quad;
        const long gr = r0 + r;
        v8s v = (v8s){0, 0, 0, 0, 0, 0, 0, 0};
        if (gr < rows) v = *(const v8s*)(in + gr * 128 + mrow * 8);
        *(v8s*)&X[r * 256 + ((mrow * 8) ^ ((r & 7) << 3))] = v;
    }
    __syncthreads();

    // GEMM1: in[64x128] @ WA[128x256]
    v4f acc[4][4];
    #pragma unroll
    for (int rb = 0; rb < 4; ++rb)
        #pragma unroll
        for (int c = 0; c < 4; ++c)
            acc[rb][c] = (v4f){0.f, 0.f, 0.f, 0.f};
    const int ct0 = wid * 4;
    #pragma unroll
    for (int kt = 0; kt < 4; ++kt) {
        v8s a[4];
        #pragma unroll
        for (int rb = 0; rb < 4; ++rb) {
            const int r = rb * 16 + mrow;
            a[rb] = *(const v8s*)&X[r * 256 + ((kt * 32 + quad * 8) ^ ((r & 7) << 3))];
        }
        #pragma unroll
        for (int c = 0; c < 4; ++c) {
            const v8s b = ((const v8s*)wpkA)[(kt * 16 + ct0 + c) * 64 + lane];
            #pragma unroll
            for (int rb = 0; rb < 4; ++rb)
                acc[rb][c] = __builtin_amdgcn_mfma_f32_16x16x32_bf16(a[rb], b, acc[rb][c], 0, 0, 0);
        }
    }
    __syncthreads();   // all GEMM1 reads of X complete before overwrite

    // BN+ReLU in-reg, write mid-tile [64][256] (OOB rows forced to zero for stats of GEMM2)
    #pragma unroll
    for (int c = 0; c < 4; ++c) {
        const int col = (ct0 + c) * 16 + mrow;
        const float av = aab[col], bv = bab[col];
        #pragma unroll
        for (int rb = 0; rb < 4; ++rb)
            #pragma unroll
            for (int r4 = 0; r4 < 4; ++r4) {
                const int r = rb * 16 + quad * 4 + r4;
                const float h = (r0 + r < rows) ? fmaxf(fmaf(av, acc[rb][c][r4], bv), 0.f) : 0.f;
                X[r * 256 + (col ^ ((r & 7) << 3))] = f2bf(h);
            }
    }
    __syncthreads();

    // GEMM2: mid[64x256] @ WB[256x128] -> out + stats
    v4f acc2[4][2];
    #pragma unroll
    for (int rb = 0; rb < 4; ++rb)
        #pragma unroll
        for (int c = 0; c < 2; ++c)
            acc2[rb][c] = (v4f){0.f, 0.f, 0.f, 0.f};
    const int ct2 = wid * 2;
    #pragma unroll
    for (int kt = 0; kt < 8; ++kt) {
        v8s a[4];
        #pragma unroll
        for (int rb = 0; rb < 4; ++rb) {
            const int r = rb * 16 + mrow;
            a[rb] = *(const v8s*)&X[r * 256 + ((kt * 32 + quad * 8) ^ ((r & 7) << 3))];
        }
        #pragma unroll
        for (int c = 0; c < 2; ++c) {
            const v8s b = ((const v8s*)wpkB)[(kt * 8 + ct2 + c) * 64 + lane];
            #pragma unroll
            for (int rb = 0; rb < 4; ++rb)
                acc2[rb][c] = __builtin_amdgcn_mfma_f32_16x16x32_bf16(a[rb], b, acc2[rb][c], 0, 0, 0);
        }
    }
    #pragma unroll
    for (int c = 0; c < 2; ++c) {
        const int col = (ct2 + c) * 16 + mrow;
        float sy = 0.f, sq = 0.f;
        #pragma unroll
        for (int rb = 0; rb < 4; ++rb) {
            #pragma unroll
            for (int r4 = 0; r4 < 4; ++r4) {
                const float v = acc2[rb][c][r4];
                const long gr = r0 + rb * 16 + quad * 4 + r4;
                if (gr < rows) out[gr * 128 + col] = f2bf(v);
                sy += v; sq += v * v;
            }
        }
        sy += __shfl_xor(sy, 16); sy += __shfl_xor(sy, 32);
        sq += __shfl_xor(sq, 16); sq += __shfl_xor(sq, 32);
        if (quad == 0) {
            atomicAdd(&sS[bin * 1792 + col], sy);
            atomicAdd(&sQ[bin * 1792 + col], sq);
        }
    }
}

// ---------------- final BN+ReLU apply -> d_out (4 channels / thread) ----------------
__global__ __launch_bounds__(256) void final_k(
    const unsigned short* __restrict__ z2, const unsigned short* __restrict__ w2,
    const float* __restrict__ ab, void* __restrict__ out, const int* __restrict__ flag)
{
    const long p = (long)blockIdx.x * 256 + threadIdx.x;   // 4-channel unit
    const long npn = (long)NN * 32;
    const long tot = npn + (long)NE * 32;
    if (p >= tot) return;
    long el, oe; const unsigned short* src; int abA, abB;
    if (p < npn) { el = p * 4; oe = el; src = z2; abA = 1536; abB = 1664; }
    else { el = (p - npn) * 4; oe = (long)NN * 128 + el; src = w2; abA = 1280; abB = 1408; }
    const int col = (int)(el & 127);
    const uint2 v = *(const uint2*)(src + el);
    const float o0 = fmaxf(fmaf(ab[abA + col],     lo16(v.x), ab[abB + col]),     0.f);
    const float o1 = fmaxf(fmaf(ab[abA + col + 1], hi16(v.x), ab[abB + col + 1]), 0.f);
    const float o2 = fmaxf(fmaf(ab[abA + col + 2], lo16(v.y), ab[abB + col + 2]), 0.f);
    const float o3 = fmaxf(fmaf(ab[abA + col + 3], hi16(v.y), ab[abB + col + 3]), 0.f);
    if (*flag) {
        uint2 r; r.x = pk2(o0, o1); r.y = pk2(o2, o3);
        *(uint2*)((unsigned short*)out + oe) = r;
    } else {
        float4 f; f.x = o0; f.y = o1; f.z = o2; f.w = o3;
        *(float4*)((float*)out + oe) = f;
    }
}

extern "C" void kernel_launch(void* const* d_in, const int* in_sizes, int n_in,
                              void* d_out, int out_size, void* d_ws, size_t ws_size,
                              hipStream_t stream)
{
    (void)in_sizes; (void)n_in; (void)out_size; (void)ws_size;
    const unsigned short* edgeR = (const unsigned short*)d_in[1];
    const int* ep = (const int*)d_in[2];

    char* ws = (char*)d_ws;
    unsigned short* wpk = (unsigned short*)ws;                      // 327,680 B
    float* stats   = (float*)(ws + 327680);                         // 229,376 B (32 bins x 1792)
    float* ab      = (float*)(ws + 557056);                         // 7,168 B
    int*   flag    = (int*)(ws + 564224);                           // 256 B
    int*   rowptr  = (int*)(ws + 564480);                           // 400,128 B
    int*   cursor  = (int*)(ws + 964608);                           // 400,128 B
    int*   csr     = (int*)(ws + 1364736);                          // 4,000,000 B
    unsigned short* y1      = (unsigned short*)(ws + 5364736);      // 128 MB
    unsigned short* edge_in = (unsigned short*)(ws + 133364736);    // 128 MB
    unsigned short* w2      = (unsigned short*)(ws + 261364736);    // 128 MB
    unsigned short* node_in = (unsigned short*)(ws + 389364736);    // 25.6 MB
    unsigned short* z2      = (unsigned short*)(ws + 414964736);    // 25.6 MB (end ~441 MB)

    const unsigned short* wpk1  = wpk;
    const unsigned short* wpkN1 = wpk + 32768;
    const unsigned short* wpkN2 = wpk + 65536;
    const unsigned short* wpkE1 = wpk + 98304;
    const unsigned short* wpkE2 = wpk + 131072;

    detect_k<<<1, 256, 0, stream>>>(edgeR, flag);
    hipMemsetAsync(stats, 0, 229376, stream);
    hipMemsetAsync(cursor, 0, 400000, stream);

    // CSR build (depends only on ep)
    hist_k<<<3907, 256, 0, stream>>>(ep, cursor);
    scan_k<<<1, 1024, 0, stream>>>(cursor, rowptr);
    fill_k<<<3907, 256, 0, stream>>>(ep, cursor, csr);

    pack_weights<<<640, 256, 0, stream>>>(d_in[3], d_in[6], d_in[9], d_in[12], d_in[15], wpk, flag);

    kernel_A<<<7813, 256, 0, stream>>>(d_in[0], d_in[1], ep, wpk1, wpkE1, y1, edge_in, stats, d_in[19], flag);
    finalize_k<<<1, 128, 0, stream>>>(stats, ab, d_in[4], d_in[5], 0, 128, 0, 128, 128, 1.f / NE, flag);
    finalize_k<<<1, 256, 0, stream>>>(stats, ab, d_in[13], d_in[14], 256, 512, 256, 512, 256, 1.f / NE, flag);

    // node branch first: y1 is still L3-warm for the CSR gather
    gemm_node1<<<1563, 256, 0, stream>>>(d_in[0], y1, rowptr, csr, wpkN1, node_in,
                                         stats + 768, stats + 1024, d_in[18], ab, flag);
    finalize_k<<<1, 256, 0, stream>>>(stats, ab, d_in[7], d_in[8], 768, 1024, 768, 1024, 256, 1.f / NN, flag);

    fused2_k<<<1563, 256, 0, stream>>>(node_in, ab + 768, ab + 1024, wpkN1, wpkN2, z2,
                                       stats + 1536, stats + 1664, (long)NN);
    finalize_k<<<1, 128, 0, stream>>>(stats, ab, d_in[10], d_in[11], 1536, 1664, 1536, 1664, 128, 1.f / NN, flag);

    // edge branch
    fused2_k<<<7813, 256, 0, stream>>>(edge_in, ab + 256, ab + 512, wpkE1, wpkE2, w2,
                                       stats + 1280, stats + 1408, (long)NE);
    finalize_k<<<1, 128, 0, stream>>>(stats, ab, d_in[16], d_in[17], 1280, 1408, 1280, 1408, 128, 1.f / NE, flag);

    final_k<<<75000, 256, 0, stream>>>(z2, w2, ab, d_out, flag);
}

// Round 3
// 1769.115 us; speedup vs baseline: 1.1650x; 1.0403x over previous
//
#include <hip/hip_runtime.h>

#define NN 100000
#define NE 500000

typedef short v8s __attribute__((ext_vector_type(8)));
typedef float v4f __attribute__((ext_vector_type(4)));
typedef unsigned u32x2 __attribute__((ext_vector_type(2)));
typedef unsigned u32x4 __attribute__((ext_vector_type(4)));
typedef float f32x4 __attribute__((ext_vector_type(4)));

__device__ __forceinline__ unsigned short f2bf(float f) {
    unsigned u = __float_as_uint(f);
    u += 0x7fffu + ((u >> 16) & 1u);
    return (unsigned short)(u >> 16);
}
__device__ __forceinline__ float bf2f(unsigned short h) {
    return __uint_as_float(((unsigned)h) << 16);
}
__device__ __forceinline__ unsigned pk2(float a, float b) {
    return (unsigned)f2bf(a) | ((unsigned)f2bf(b) << 16);
}
__device__ __forceinline__ float lo16(unsigned v) { return bf2f((unsigned short)(v & 0xffffu)); }
__device__ __forceinline__ float hi16(unsigned v) { return bf2f((unsigned short)(v >> 16)); }

// load channels (2*lane, 2*lane+1) of row `row` of a [rows,128] tensor (bf16 or f32)
__device__ __forceinline__ unsigned load2(const void* base, long row, int lane, int f) {
    if (f) return ((const unsigned*)base)[row * 64 + lane];
    const float2 v = ((const float2*)base)[row * 64 + lane];
    return pk2(v.x, v.y);
}

// ---------------- dtype detector ----------------
__global__ void detect_k(const unsigned short* __restrict__ edgeR, int* __restrict__ flag) {
    __shared__ int cnt;
    const int tid = threadIdx.x;
    if (tid == 0) cnt = 0;
    __syncthreads();
    const float v = fabsf(bf2f(edgeR[2 * tid]));
    const int sane = (v > 1e-5f && v < 100.f) ? 1 : 0;
    atomicAdd(&cnt, sane);
    __syncthreads();
    if (tid == 0) *flag = (cnt >= 128) ? 1 : 0;
}

// ---------------- CSR build: histogram -> scan -> fill ----------------
__global__ __launch_bounds__(256) void hist_k(const int* __restrict__ ep, int* __restrict__ deg) {
    const int i = blockIdx.x * 256 + threadIdx.x;
    if (i < 2 * NE) atomicAdd(&deg[ep[i]], 1);
}

__global__ __launch_bounds__(1024) void scan_k(int* __restrict__ degcur, int* __restrict__ rowptr) {
    __shared__ int sd[1024];
    const int t = threadIdx.x;
    const int base = t * 98;
    int sum = 0;
    for (int i = 0; i < 98; ++i) {
        const int idx = base + i;
        if (idx < NN) sum += degcur[idx];
    }
    sd[t] = sum;
    __syncthreads();
    for (int off = 1; off < 1024; off <<= 1) {
        const int v = (t >= off) ? sd[t - off] : 0;
        __syncthreads();
        sd[t] += v;
        __syncthreads();
    }
    int run = sd[t] - sum;   // exclusive prefix of this chunk
    for (int i = 0; i < 98; ++i) {
        const int idx = base + i;
        if (idx < NN) {
            const int d = degcur[idx];   // read BEFORE overwrite
            rowptr[idx] = run;
            degcur[idx] = run;           // becomes the fill cursor
            run += d;
        }
    }
    if (t == 0) rowptr[NN] = 2 * NE;
}

__global__ __launch_bounds__(256) void fill_k(const int* __restrict__ ep,
                                              int* __restrict__ cursor, int* __restrict__ csr) {
    const int i = blockIdx.x * 256 + threadIdx.x;
    if (i >= 2 * NE) return;
    const int n = ep[i];
    const int pos = atomicAdd(&cursor[n], 1);
    csr[pos] = (i < NE) ? i : (i - NE);
}

// ---------------- pack weights into MFMA B-fragment order ----------------
__global__ __launch_bounds__(256) void pack_weights(
    const void* __restrict__ W1, const void* __restrict__ Wn1,
    const void* __restrict__ Wn2, const void* __restrict__ We1,
    const void* __restrict__ We2, unsigned short* __restrict__ wpk,
    const int* __restrict__ flag)
{
    const int i = blockIdx.x * 256 + threadIdx.x;
    if (i >= 163840) return;
    const void* W; int Nn; int li = i;
    if (i < 32768)       { W = W1;  Nn = 128; }
    else if (i < 65536)  { W = Wn1; Nn = 256; li -= 32768; }
    else if (i < 98304)  { W = Wn2; Nn = 128; li -= 65536; }
    else if (i < 131072) { W = We1; Nn = 256; li -= 98304; }
    else                 { W = We2; Nn = 128; li -= 131072; }
    const int ntn = Nn >> 4;
    const int j = li & 7, l = (li >> 3) & 63, tile = li >> 9;
    const int ct = tile % ntn, kt = tile / ntn;
    const int k = kt * 32 + (l >> 4) * 8 + j;
    const int n = ct * 16 + (l & 15);
    const int idx = k * Nn + n;
    wpk[i] = (*flag) ? ((const unsigned short*)W)[idx]
                     : f2bf(((const float*)W)[idx]);
}

// ---------------- kernel A: gather + concat GEMM (lvl_mlp_1) + edge GEMM_e1 (stats only) ----------
// LDS: [64][256] shorts, XOR-swizzled (c ^= (row&7)<<3) -> exactly 32 KiB -> 5 blocks/CU
__global__ __launch_bounds__(256, 5) void kernel_A(
    const void* __restrict__ node, const void* __restrict__ edge,
    const int* __restrict__ ep,
    const unsigned short* __restrict__ wpk1, const unsigned short* __restrict__ wpkE1,
    unsigned short* __restrict__ y1, unsigned short* __restrict__ edge_in,
    float* __restrict__ stats, const void* __restrict__ eps2p, const int* __restrict__ flag)
{
    __shared__ unsigned short X[64 * 256];
    const int tid = threadIdx.x, wid = tid >> 6, lane = tid & 63;
    const int mrow = lane & 15, quad = lane >> 4;
    const int li = lane & 31, hb = lane >> 5;
    const int e0 = blockIdx.x * 64;
    const int e0w = e0 + wid * 16;
    const int bin = blockIdx.x & 31;
    const int f = *flag;

    // one coalesced endpoint-index load per wave (lanes 0..15 carry the 16 edges)
    const int ei = e0w + mrow;
    int sv = 0, tv = 0;
    if (ei < NE) { sv = ep[ei]; tv = ep[NE + ei]; }

    // gather: 2 rows per instruction (half-wave per row), 16B loads
    #pragma unroll
    for (int j = 0; j < 8; ++j) {
        const int eA = e0w + 2 * j + hb;
        const int s = __shfl(sv, 2 * j + hb);
        const int t = __shfl(tv, 2 * j + hb);
        u32x2 lp = {0u, 0u}, ee = {0u, 0u};
        if (eA < NE) {
            if (f) {
                const u32x2 a = *(const u32x2*)((const unsigned*)node + (size_t)s * 64 + li * 2);
                const u32x2 b = *(const u32x2*)((const unsigned*)node + (size_t)t * 64 + li * 2);
                ee = __builtin_nontemporal_load((const u32x2*)((const unsigned*)edge + (size_t)eA * 64 + li * 2));
                lp.x = pk2(lo16(a.x) + lo16(b.x), hi16(a.x) + hi16(b.x));
                lp.y = pk2(lo16(a.y) + lo16(b.y), hi16(a.y) + hi16(b.y));
            } else {
                const f32x4 a = *(const f32x4*)((const float*)node + (size_t)s * 128 + li * 4);
                const f32x4 b = *(const f32x4*)((const float*)node + (size_t)t * 128 + li * 4);
                const f32x4 ev = __builtin_nontemporal_load((const f32x4*)((const float*)edge + (size_t)eA * 128 + li * 4));
                lp.x = pk2(a.x + b.x, a.y + b.y);
                lp.y = pk2(a.z + b.z, a.w + b.w);
                ee.x = pk2(ev.x, ev.y);
                ee.y = pk2(ev.z, ev.w);
            }
        }
        const int r = wid * 16 + 2 * j + hb;
        const int swz = (r & 7) << 3;
        *(u32x2*)&X[r * 256 + ((li * 4) ^ swz)] = lp;
        *(u32x2*)&X[r * 256 + ((128 + li * 4) ^ swz)] = ee;
    }
    __syncthreads();

    // GEMM1: X[64x256] @ W_lvl1[256x128] -> y1 + stats
    {
        v4f acc[4][2];
        #pragma unroll
        for (int rb = 0; rb < 4; ++rb)
            #pragma unroll
            for (int c = 0; c < 2; ++c)
                acc[rb][c] = (v4f){0.f, 0.f, 0.f, 0.f};
        const int ct0 = wid * 2;
        #pragma unroll
        for (int kt = 0; kt < 8; ++kt) {
            v8s a[4];
            #pragma unroll
            for (int rb = 0; rb < 4; ++rb) {
                const int r = rb * 16 + mrow;
                a[rb] = *(const v8s*)&X[r * 256 + ((kt * 32 + quad * 8) ^ ((r & 7) << 3))];
            }
            #pragma unroll
            for (int c = 0; c < 2; ++c) {
                const v8s b = ((const v8s*)wpk1)[(kt * 8 + ct0 + c) * 64 + lane];
                #pragma unroll
                for (int rb = 0; rb < 4; ++rb)
                    acc[rb][c] = __builtin_amdgcn_mfma_f32_16x16x32_bf16(a[rb], b, acc[rb][c], 0, 0, 0);
            }
        }
        #pragma unroll
        for (int c = 0; c < 2; ++c) {
            const int col = (ct0 + c) * 16 + mrow;
            float sy = 0.f, sq = 0.f;
            #pragma unroll
            for (int rb = 0; rb < 4; ++rb) {
                #pragma unroll
                for (int r4 = 0; r4 < 4; ++r4) {
                    const float v = acc[rb][c][r4];
                    const int e = e0 + rb * 16 + quad * 4 + r4;
                    if (e < NE) __builtin_nontemporal_store(f2bf(v), &y1[(size_t)e * 128 + col]);
                    sy += v; sq += v * v;
                }
            }
            sy += __shfl_xor(sy, 16); sy += __shfl_xor(sy, 32);
            sq += __shfl_xor(sq, 16); sq += __shfl_xor(sq, 32);
            if (quad == 0) {
                atomicAdd(&stats[bin * 1792 + col], sy);
                atomicAdd(&stats[bin * 1792 + 128 + col], sq);
            }
        }
    }
    __syncthreads();

    // rebuild edge_in = (1+eps2)*edge + lift into cols [0,128) and store to global (NT)
    const float e2 = 1.f + (f ? bf2f(((const unsigned short*)eps2p)[0])
                              : ((const float*)eps2p)[0]);
    #pragma unroll
    for (int rr = 0; rr < 16; ++rr) {
        const int r = wid * 16 + rr;
        const int swz = (r & 7) << 3;
        const unsigned lp = *(const unsigned*)&X[r * 256 + ((2 * lane) ^ swz)];
        const unsigned ee = *(const unsigned*)&X[r * 256 + ((128 + 2 * lane) ^ swz)];
        const unsigned o = pk2(fmaf(e2, lo16(ee), lo16(lp)), fmaf(e2, hi16(ee), hi16(lp)));
        *(unsigned*)&X[r * 256 + ((2 * lane) ^ swz)] = o;
        const int e = e0 + r;
        if (e < NE) __builtin_nontemporal_store(o, &((unsigned*)edge_in)[(size_t)e * 64 + lane]);
    }
    __syncthreads();

    // GEMM_e1: edge_in[64x128] @ W_e1[128x256] -> stats ONLY (output recomputed in fused pass 2)
    {
        v4f acc[4][4];
        #pragma unroll
        for (int rb = 0; rb < 4; ++rb)
            #pragma unroll
            for (int c = 0; c < 4; ++c)
                acc[rb][c] = (v4f){0.f, 0.f, 0.f, 0.f};
        const int ct0 = wid * 4;
        #pragma unroll
        for (int kt = 0; kt < 4; ++kt) {
            v8s a[4];
            #pragma unroll
            for (int rb = 0; rb < 4; ++rb) {
                const int r = rb * 16 + mrow;
                a[rb] = *(const v8s*)&X[r * 256 + ((kt * 32 + quad * 8) ^ ((r & 7) << 3))];
            }
            #pragma unroll
            for (int c = 0; c < 4; ++c) {
                const v8s b = ((const v8s*)wpkE1)[(kt * 16 + ct0 + c) * 64 + lane];
                #pragma unroll
                for (int rb = 0; rb < 4; ++rb)
                    acc[rb][c] = __builtin_amdgcn_mfma_f32_16x16x32_bf16(a[rb], b, acc[rb][c], 0, 0, 0);
            }
        }
        #pragma unroll
        for (int c = 0; c < 4; ++c) {
            const int col = (ct0 + c) * 16 + mrow;
            float sy = 0.f, sq = 0.f;
            #pragma unroll
            for (int rb = 0; rb < 4; ++rb) {
                #pragma unroll
                for (int r4 = 0; r4 < 4; ++r4) {
                    const float v = acc[rb][c][r4];   // OOB rows are zero in X -> contribute 0
                    sy += v; sq += v * v;
                }
            }
            sy += __shfl_xor(sy, 16); sy += __shfl_xor(sy, 32);
            sq += __shfl_xor(sq, 16); sq += __shfl_xor(sq, 32);
            if (quad == 0) {
                atomicAdd(&stats[bin * 1792 + 256 + col], sy);
                atomicAdd(&stats[bin * 1792 + 512 + col], sq);
            }
        }
    }
}

// ---------------- finalize BN ----------------
__global__ void finalize_k(const float* __restrict__ stats, float* __restrict__ ab,
                           const void* __restrict__ g, const void* __restrict__ bb,
                           const int sOff, const int qOff, const int aOff, const int bOff,
                           const int n, const float invc, const int* __restrict__ flag)
{
    const int c = threadIdx.x;
    if (c >= n) return;
    float S = 0.f, Q = 0.f;
    for (int b = 0; b < 32; ++b) { S += stats[b * 1792 + sOff + c]; Q += stats[b * 1792 + qOff + c]; }
    const float mu = S * invc;
    const float var = Q * invc - mu * mu;
    const float gv = (*flag) ? bf2f(((const unsigned short*)g)[c]) : ((const float*)g)[c];
    const float bv = (*flag) ? bf2f(((const unsigned short*)bb)[c]) : ((const float*)bb)[c];
    const float a = gv * rsqrtf(var + 1e-5f);
    ab[aOff + c] = a;
    ab[bOff + c] = bv - a * mu;
}

// ---------------- node MLP layer 1 with fused CSR gather (stats only + node_in store) ----------
__global__ __launch_bounds__(256, 5) void gemm_node1(
    const void* __restrict__ node, const unsigned short* __restrict__ y1,
    const int* __restrict__ rowptr, const int* __restrict__ csr,
    const unsigned short* __restrict__ wpk, unsigned short* __restrict__ node_in,
    float* __restrict__ sS, float* __restrict__ sQ,
    const void* __restrict__ eps1p, const float* __restrict__ ab,
    const int* __restrict__ flag)
{
    __shared__ unsigned short X[64 * 128];   // [64][128] swizzled, 16 KiB
    const int tid = threadIdx.x, wid = tid >> 6, lane = tid & 63;
    const int mrow = lane & 15, quad = lane >> 4;
    const long r0 = (long)blockIdx.x * 64;
    const int bin = blockIdx.x & 31;
    const int f = *flag;
    const float ea = 1.f + (f ? bf2f(((const unsigned short*)eps1p)[0])
                              : ((const float*)eps1p)[0]);
    const int c0 = 2 * lane;
    const float a0 = ab[c0], a1 = ab[c0 + 1];
    const float b0 = ab[128 + c0], b1 = ab[128 + c0 + 1];

    for (int rr = 0; rr < 16; ++rr) {
        const int r = wid * 16 + rr;
        const long gr = r0 + r;
        unsigned o = 0;
        if (gr < NN) {
            float s0 = 0.f, s1 = 0.f;
            const int beg = rowptr[gr], end = rowptr[gr + 1];
            for (int i = beg; i < end; ++i) {
                const int e = csr[i];
                const unsigned v = ((const unsigned*)y1)[(size_t)e * 64 + lane];
                s0 += fmaxf(fmaf(a0, lo16(v), b0), 0.f);
                s1 += fmaxf(fmaf(a1, hi16(v), b1), 0.f);
            }
            const unsigned nr = load2(node, gr, lane, f);
            o = pk2(fmaf(ea, lo16(nr), s0), fmaf(ea, hi16(nr), s1));
        }
        *(unsigned*)&X[r * 128 + ((2 * lane) ^ ((r & 7) << 3))] = o;
        if (gr < NN) __builtin_nontemporal_store(o, &((unsigned*)node_in)[gr * 64 + lane]);
    }
    __syncthreads();

    v4f acc[4][4];
    #pragma unroll
    for (int rb = 0; rb < 4; ++rb)
        #pragma unroll
        for (int c = 0; c < 4; ++c)
            acc[rb][c] = (v4f){0.f, 0.f, 0.f, 0.f};
    const int ct0 = wid * 4;
    #pragma unroll
    for (int kt = 0; kt < 4; ++kt) {
        v8s a[4];
        #pragma unroll
        for (int rb = 0; rb < 4; ++rb) {
            const int r = rb * 16 + mrow;
            a[rb] = *(const v8s*)&X[r * 128 + ((kt * 32 + quad * 8) ^ ((r & 7) << 3))];
        }
        #pragma unroll
        for (int c = 0; c < 4; ++c) {
            const v8s b = ((const v8s*)wpk)[(kt * 16 + ct0 + c) * 64 + lane];
            #pragma unroll
            for (int rb = 0; rb < 4; ++rb)
                acc[rb][c] = __builtin_amdgcn_mfma_f32_16x16x32_bf16(a[rb], b, acc[rb][c], 0, 0, 0);
        }
    }
    #pragma unroll
    for (int c = 0; c < 4; ++c) {
        const int col = (ct0 + c) * 16 + mrow;
        float sy = 0.f, sq = 0.f;
        #pragma unroll
        for (int rb = 0; rb < 4; ++rb) {
            #pragma unroll
            for (int r4 = 0; r4 < 4; ++r4) {
                const float v = acc[rb][c][r4];
                sy += v; sq += v * v;
            }
        }
        sy += __shfl_xor(sy, 16); sy += __shfl_xor(sy, 32);
        sq += __shfl_xor(sq, 16); sq += __shfl_xor(sq, 32);
        if (quad == 0) {
            atomicAdd(&sS[bin * 1792 + col], sy);
            atomicAdd(&sQ[bin * 1792 + col], sq);
        }
    }
}

// ---------------- fused pass-2: in[rows,128] -> GEMM1(128->256) -> BN+ReLU -> GEMM2(256->128) ----
__global__ __launch_bounds__(256, 5) void fused2_k(
    const unsigned short* __restrict__ in, const float* __restrict__ aab,
    const float* __restrict__ bab, const unsigned short* __restrict__ wpkA,
    const unsigned short* __restrict__ wpkB, unsigned short* __restrict__ out,
    float* __restrict__ sS, float* __restrict__ sQ, const long rows)
{
    __shared__ unsigned short X[64 * 256];   // 32 KiB, swizzled; in-tile -> mid-tile -> out-tile
    const int tid = threadIdx.x, wid = tid >> 6, lane = tid & 63;
    const int mrow = lane & 15, quad = lane >> 4;
    const long r0 = (long)blockIdx.x * 64;
    const int bin = blockIdx.x & 31;

    // phase 1: load in-tile [64][128] into cols [0,128) (NT, 4 rows per 16B instruction)
    #pragma unroll
    for (int i = 0; i < 4; ++i) {
        const int r = wid * 16 + i * 4 + quad;
        const long gr = r0 + r;
        v8s v = (v8s){0, 0, 0, 0, 0, 0, 0, 0};
        if (gr < rows) v = __builtin_nontemporal_load((const v8s*)(in + gr * 128 + mrow * 8));
        *(v8s*)&X[r * 256 + ((mrow * 8) ^ ((r & 7) << 3))] = v;
    }
    __syncthreads();

    // GEMM1: in[64x128] @ WA[128x256]
    v4f acc[4][4];
    #pragma unroll
    for (int rb = 0; rb < 4; ++rb)
        #pragma unroll
        for (int c = 0; c < 4; ++c)
            acc[rb][c] = (v4f){0.f, 0.f, 0.f, 0.f};
    const int ct0 = wid * 4;
    #pragma unroll
    for (int kt = 0; kt < 4; ++kt) {
        v8s a[4];
        #pragma unroll
        for (int rb = 0; rb < 4; ++rb) {
            const int r = rb * 16 + mrow;
            a[rb] = *(const v8s*)&X[r * 256 + ((kt * 32 + quad * 8) ^ ((r & 7) << 3))];
        }
        #pragma unroll
        for (int c = 0; c < 4; ++c) {
            const v8s b = ((const v8s*)wpkA)[(kt * 16 + ct0 + c) * 64 + lane];
            #pragma unroll
            for (int rb = 0; rb < 4; ++rb)
                acc[rb][c] = __builtin_amdgcn_mfma_f32_16x16x32_bf16(a[rb], b, acc[rb][c], 0, 0, 0);
        }
    }
    __syncthreads();   // all GEMM1 reads of X complete before overwrite

    // BN+ReLU in-reg, write mid-tile [64][256] (OOB rows forced to zero for stats of GEMM2)
    #pragma unroll
    for (int c = 0; c < 4; ++c) {
        const int col = (ct0 + c) * 16 + mrow;
        const float av = aab[col], bv = bab[col];
        #pragma unroll
        for (int rb = 0; rb < 4; ++rb)
            #pragma unroll
            for (int r4 = 0; r4 < 4; ++r4) {
                const int r = rb * 16 + quad * 4 + r4;
                const float h = (r0 + r < rows) ? fmaxf(fmaf(av, acc[rb][c][r4], bv), 0.f) : 0.f;
                X[r * 256 + (col ^ ((r & 7) << 3))] = f2bf(h);
            }
    }
    __syncthreads();

    // GEMM2: mid[64x256] @ WB[256x128] -> stats + staged coalesced out
    v4f acc2[4][2];
    #pragma unroll
    for (int rb = 0; rb < 4; ++rb)
        #pragma unroll
        for (int c = 0; c < 2; ++c)
            acc2[rb][c] = (v4f){0.f, 0.f, 0.f, 0.f};
    const int ct2 = wid * 2;
    #pragma unroll
    for (int kt = 0; kt < 8; ++kt) {
        v8s a[4];
        #pragma unroll
        for (int rb = 0; rb < 4; ++rb) {
            const int r = rb * 16 + mrow;
            a[rb] = *(const v8s*)&X[r * 256 + ((kt * 32 + quad * 8) ^ ((r & 7) << 3))];
        }
        #pragma unroll
        for (int c = 0; c < 2; ++c) {
            const v8s b = ((const v8s*)wpkB)[(kt * 8 + ct2 + c) * 64 + lane];
            #pragma unroll
            for (int rb = 0; rb < 4; ++rb)
                acc2[rb][c] = __builtin_amdgcn_mfma_f32_16x16x32_bf16(a[rb], b, acc2[rb][c], 0, 0, 0);
        }
    }
    // stats from registers
    #pragma unroll
    for (int c = 0; c < 2; ++c) {
        const int col = (ct2 + c) * 16 + mrow;
        float sy = 0.f, sq = 0.f;
        #pragma unroll
        for (int rb = 0; rb < 4; ++rb) {
            #pragma unroll
            for (int r4 = 0; r4 < 4; ++r4) {
                const float v = acc2[rb][c][r4];
                sy += v; sq += v * v;
            }
        }
        sy += __shfl_xor(sy, 16); sy += __shfl_xor(sy, 32);
        sq += __shfl_xor(sq, 16); sq += __shfl_xor(sq, 32);
        if (quad == 0) {
            atomicAdd(&sS[bin * 1792 + col], sy);
            atomicAdd(&sQ[bin * 1792 + col], sq);
        }
    }
    __syncthreads();   // GEMM2 reads of X done -> reuse X as out-stage

    // stage out-tile [64][128] into X (cols 0..127, swizzled)
    #pragma unroll
    for (int c = 0; c < 2; ++c) {
        const int col = (ct2 + c) * 16 + mrow;
        #pragma unroll
        for (int rb = 0; rb < 4; ++rb)
            #pragma unroll
            for (int r4 = 0; r4 < 4; ++r4) {
                const int r = rb * 16 + quad * 4 + r4;
                X[r * 256 + (col ^ ((r & 7) << 3))] = f2bf(acc2[rb][c][r4]);
            }
    }
    __syncthreads();

    // coalesced NT store: 16 lanes x 16B = full 256B rows
    #pragma unroll
    for (int i = 0; i < 4; ++i) {
        const int r = wid * 16 + i * 4 + quad;
        const long gr = r0 + r;
        if (gr < rows) {
            const u32x4 v = *(const u32x4*)&X[r * 256 + ((mrow * 8) ^ ((r & 7) << 3))];
            __builtin_nontemporal_store(v, (u32x4*)(out + gr * 128 + mrow * 8));
        }
    }
}

// ---------------- final BN+ReLU apply -> d_out (8 channels / thread, NT) ----------------
__global__ __launch_bounds__(256) void final_k(
    const unsigned short* __restrict__ z2, const unsigned short* __restrict__ w2,
    const float* __restrict__ ab, void* __restrict__ out, const int* __restrict__ flag)
{
    const long p = (long)blockIdx.x * 256 + threadIdx.x;   // 8-channel unit
    const long npn = (long)NN * 16;
    const long tot = npn + (long)NE * 16;
    if (p >= tot) return;
    long el, oe; const unsigned short* src; int abA, abB;
    if (p < npn) { el = p * 8; oe = el; src = z2; abA = 1536; abB = 1664; }
    else { el = (p - npn) * 8; oe = (long)NN * 128 + el; src = w2; abA = 1280; abB = 1408; }
    const int col = (int)(el & 127);
    const u32x4 v = __builtin_nontemporal_load((const u32x4*)(src + el));
    float o[8];
    #pragma unroll
    for (int i = 0; i < 4; ++i) {
        o[2 * i]     = fmaxf(fmaf(ab[abA + col + 2 * i],     lo16(v[i]), ab[abB + col + 2 * i]),     0.f);
        o[2 * i + 1] = fmaxf(fmaf(ab[abA + col + 2 * i + 1], hi16(v[i]), ab[abB + col + 2 * i + 1]), 0.f);
    }
    if (*flag) {
        u32x4 r;
        #pragma unroll
        for (int i = 0; i < 4; ++i) r[i] = pk2(o[2 * i], o[2 * i + 1]);
        __builtin_nontemporal_store(r, (u32x4*)((unsigned short*)out + oe));
    } else {
        f32x4 r0, r1;
        r0.x = o[0]; r0.y = o[1]; r0.z = o[2]; r0.w = o[3];
        r1.x = o[4]; r1.y = o[5]; r1.z = o[6]; r1.w = o[7];
        float* op = (float*)out + oe;
        __builtin_nontemporal_store(r0, (f32x4*)op);
        __builtin_nontemporal_store(r1, (f32x4*)(op + 4));
    }
}

extern "C" void kernel_launch(void* const* d_in, const int* in_sizes, int n_in,
                              void* d_out, int out_size, void* d_ws, size_t ws_size,
                              hipStream_t stream)
{
    (void)in_sizes; (void)n_in; (void)out_size; (void)ws_size;
    const unsigned short* edgeR = (const unsigned short*)d_in[1];
    const int* ep = (const int*)d_in[2];

    char* ws = (char*)d_ws;
    unsigned short* wpk = (unsigned short*)ws;                      // 327,680 B
    float* stats   = (float*)(ws + 327680);                         // 229,376 B (32 bins x 1792)
    float* ab      = (float*)(ws + 557056);                         // 7,168 B
    int*   flag    = (int*)(ws + 564224);                           // 256 B
    int*   rowptr  = (int*)(ws + 564480);                           // 400,128 B
    int*   cursor  = (int*)(ws + 964608);                           // 400,128 B
    int*   csr     = (int*)(ws + 1364736);                          // 4,000,000 B
    unsigned short* y1      = (unsigned short*)(ws + 5364736);      // 128 MB
    unsigned short* edge_in = (unsigned short*)(ws + 133364736);    // 128 MB
    unsigned short* w2      = (unsigned short*)(ws + 261364736);    // 128 MB
    unsigned short* node_in = (unsigned short*)(ws + 389364736);    // 25.6 MB
    unsigned short* z2      = (unsigned short*)(ws + 414964736);    // 25.6 MB (end ~441 MB)

    const unsigned short* wpk1  = wpk;
    const unsigned short* wpkN1 = wpk + 32768;
    const unsigned short* wpkN2 = wpk + 65536;
    const unsigned short* wpkE1 = wpk + 98304;
    const unsigned short* wpkE2 = wpk + 131072;

    detect_k<<<1, 256, 0, stream>>>(edgeR, flag);
    hipMemsetAsync(stats, 0, 229376, stream);
    hipMemsetAsync(cursor, 0, 400000, stream);

    // CSR build (depends only on ep)
    hist_k<<<3907, 256, 0, stream>>>(ep, cursor);
    scan_k<<<1, 1024, 0, stream>>>(cursor, rowptr);
    fill_k<<<3907, 256, 0, stream>>>(ep, cursor, csr);

    pack_weights<<<640, 256, 0, stream>>>(d_in[3], d_in[6], d_in[9], d_in[12], d_in[15], wpk, flag);

    kernel_A<<<7813, 256, 0, stream>>>(d_in[0], d_in[1], ep, wpk1, wpkE1, y1, edge_in, stats, d_in[19], flag);
    finalize_k<<<1, 128, 0, stream>>>(stats, ab, d_in[4], d_in[5], 0, 128, 0, 128, 128, 1.f / NE, flag);
    finalize_k<<<1, 256, 0, stream>>>(stats, ab, d_in[13], d_in[14], 256, 512, 256, 512, 256, 1.f / NE, flag);

    // node branch first: y1 is still L3-warm for the CSR gather
    gemm_node1<<<1563, 256, 0, stream>>>(d_in[0], y1, rowptr, csr, wpkN1, node_in,
                                         stats + 768, stats + 1024, d_in[18], ab, flag);
    finalize_k<<<1, 256, 0, stream>>>(stats, ab, d_in[7], d_in[8], 768, 1024, 768, 1024, 256, 1.f / NN, flag);

    fused2_k<<<1563, 256, 0, stream>>>(node_in, ab + 768, ab + 1024, wpkN1, wpkN2, z2,
                                       stats + 1536, stats + 1664, (long)NN);
    finalize_k<<<1, 128, 0, stream>>>(stats, ab, d_in[10], d_in[11], 1536, 1664, 1536, 1664, 128, 1.f / NN, flag);

    // edge branch
    fused2_k<<<7813, 256, 0, stream>>>(edge_in, ab + 256, ab + 512, wpkE1, wpkE2, w2,
                                       stats + 1280, stats + 1408, (long)NE);
    finalize_k<<<1, 128, 0, stream>>>(stats, ab, d_in[16], d_in[17], 1280, 1408, 1280, 1408, 128, 1.f / NE, flag);

    final_k<<<37500, 256, 0, stream>>>(z2, w2, ab, d_out, flag);
}